// Round 1
// baseline (331.948 us; speedup 1.0000x reference)
//
#include <hip/hip_runtime.h>
#include <stdint.h>

#define N_PTS 1000000
#define B_SEG 64
#define HID 128
#define AFFD 16
#define AH 64
#define AL 32
#define AA 8
#define TPB 128       // threads per block (2 waves)
#define P 4           // points per thread
#define PTS_BLK (TPB * P)  // 512

// Output flat offsets in FLOAT elements (return order: affordances, recon_pos,
// coh_signal, coh_spatial, agent_action, agent_h_next). Output dtype: float32.
#define O_AFF 0
#define O_REC (16 * N_PTS)
#define O_SIG (19 * N_PTS)
#define O_SPA (19 * N_PTS + B_SEG)
#define O_ACT (20 * N_PTS + B_SEG)
#define O_HN  (20 * N_PTS + B_SEG + B_SEG * AA)

// ---------------------------------------------------------------------------
// Kernel 1: per-point MLPs.
// R5 lesson: 256-thread blocks + launch_bounds(256,2) made the compiler pick
// 128 VGPR and spill the ~180-reg P=8 working set to scratch.
// R6 (this round): occupancy was the limiter, not VALU work. 977 blocks gave
// only ~3.8 blocks/CU = ~1.1 waves/SIMD (Occupancy 13.9%), so VALUBusy stuck
// at 55% with every ds_read/dep bubble exposed. P=8 -> P=4 halves the working
// set (aff[4][16]=64 regs, total ~114) so launch_bounds(128,4) can cap VGPR
// at 128 WITHOUT spilling, and doubles the grid to 1954 blocks (~7.6/CU).
// LDS 20.5 KiB caps residency at 7 blocks/CU = 14 waves/CU (43.75%).
// ws layout: [seg][18] = {err_sum, count, aff_sum[16]}   (fp32)
// ---------------------------------------------------------------------------
__global__ __launch_bounds__(TPB, 4) void point_kernel(
    const float* __restrict__ pos, const int* __restrict__ batch,
    const float* __restrict__ Wf1, const float* __restrict__ bf1v,
    const float* __restrict__ Wf2, const float* __restrict__ bf2v,
    const float* __restrict__ Wg1, const float* __restrict__ bg1v,
    const float* __restrict__ Wg2, const float* __restrict__ bg2v,
    float* __restrict__ out, float* __restrict__ ws) {
  __shared__ float sF1[HID * 4];    // j*4: Wf1[0][j], Wf1[1][j], Wf1[2][j], bf1[j]
  __shared__ float sF2[HID * AFFD]; // j*16+k : Wf2[j][k]
  __shared__ float sG1[HID * AFFD]; // j*16+k : Wg1[k][j]  (transposed)
  __shared__ float sG2[HID * 4];    // j*4: Wg2[j][0..2], bg1[j]
  __shared__ float sBf2[AFFD];

  const int tid = threadIdx.x;
  for (int j = tid; j < HID; j += TPB) {
    sF1[j * 4 + 0] = Wf1[0 * HID + j];
    sF1[j * 4 + 1] = Wf1[1 * HID + j];
    sF1[j * 4 + 2] = Wf1[2 * HID + j];
    sF1[j * 4 + 3] = bf1v[j];
    sG2[j * 4 + 0] = Wg2[j * 3 + 0];
    sG2[j * 4 + 1] = Wg2[j * 3 + 1];
    sG2[j * 4 + 2] = Wg2[j * 3 + 2];
    sG2[j * 4 + 3] = bg1v[j];
  }
  for (int i = tid; i < HID * AFFD; i += TPB) {
    sF2[i] = Wf2[i];
    int j = i >> 4, k = i & 15;
    sG1[i] = Wg1[k * HID + j];
  }
  if (tid < AFFD) sBf2[tid] = bf2v[tid];
  const float bg20 = bg2v[0], bg21 = bg2v[1], bg22 = bg2v[2];
  __syncthreads();

  const float4* sF1v = (const float4*)sF1;
  const float4* sG2v = (const float4*)sG2;
  const float4* sF2v = (const float4*)sF2;
  const float4* sG1v = (const float4*)sG1;

  const int base = blockIdx.x * PTS_BLK;

  float px[P], py[P], pz[P];
  int seg[P];
  bool val[P];
#pragma unroll
  for (int i = 0; i < P; i++) {
    int p = base + i * TPB + tid;
    val[i] = (p < N_PTS);
    if (!val[i]) p = N_PTS - 1;  // clamp: uniform control flow in hot loops
    px[i] = pos[p * 3 + 0];
    py[i] = pos[p * 3 + 1];
    pz[i] = pos[p * 3 + 2];
    seg[i] = batch[p];
  }

  float aff[P][AFFD];
#pragma unroll
  for (int i = 0; i < P; i++)
#pragma unroll
    for (int k = 0; k < AFFD; k++) aff[i][k] = sBf2[k];

  // F: 3 -> 128 (relu) -> 16.  5 broadcast LDS reads feed 80 FMAs.
#pragma unroll 2
  for (int j = 0; j < HID; j++) {
    const float4 w = sF1v[j];
    const float4 r0 = sF2v[j * 4 + 0];
    const float4 r1 = sF2v[j * 4 + 1];
    const float4 r2 = sF2v[j * 4 + 2];
    const float4 r3 = sF2v[j * 4 + 3];
#pragma unroll
    for (int i = 0; i < P; i++) {
      float h = fmaf(px[i], w.x, fmaf(py[i], w.y, fmaf(pz[i], w.z, w.w)));
      h = fmaxf(h, 0.f);
      aff[i][0]  = fmaf(h, r0.x, aff[i][0]);  aff[i][1]  = fmaf(h, r0.y, aff[i][1]);
      aff[i][2]  = fmaf(h, r0.z, aff[i][2]);  aff[i][3]  = fmaf(h, r0.w, aff[i][3]);
      aff[i][4]  = fmaf(h, r1.x, aff[i][4]);  aff[i][5]  = fmaf(h, r1.y, aff[i][5]);
      aff[i][6]  = fmaf(h, r1.z, aff[i][6]);  aff[i][7]  = fmaf(h, r1.w, aff[i][7]);
      aff[i][8]  = fmaf(h, r2.x, aff[i][8]);  aff[i][9]  = fmaf(h, r2.y, aff[i][9]);
      aff[i][10] = fmaf(h, r2.z, aff[i][10]); aff[i][11] = fmaf(h, r2.w, aff[i][11]);
      aff[i][12] = fmaf(h, r3.x, aff[i][12]); aff[i][13] = fmaf(h, r3.y, aff[i][13]);
      aff[i][14] = fmaf(h, r3.z, aff[i][14]); aff[i][15] = fmaf(h, r3.w, aff[i][15]);
    }
  }

  // G: 16 -> 128 (relu) -> 3.
  float rc0[P], rc1[P], rc2[P];
#pragma unroll
  for (int i = 0; i < P; i++) { rc0[i] = bg20; rc1[i] = bg21; rc2[i] = bg22; }
#pragma unroll 2
  for (int j = 0; j < HID; j++) {
    const float4 g = sG2v[j];
    const float4 r0 = sG1v[j * 4 + 0];
    const float4 r1 = sG1v[j * 4 + 1];
    const float4 r2 = sG1v[j * 4 + 2];
    const float4 r3 = sG1v[j * 4 + 3];
#pragma unroll
    for (int i = 0; i < P; i++) {
      float h = g.w;
      h = fmaf(aff[i][0], r0.x, h);  h = fmaf(aff[i][1], r0.y, h);
      h = fmaf(aff[i][2], r0.z, h);  h = fmaf(aff[i][3], r0.w, h);
      h = fmaf(aff[i][4], r1.x, h);  h = fmaf(aff[i][5], r1.y, h);
      h = fmaf(aff[i][6], r1.z, h);  h = fmaf(aff[i][7], r1.w, h);
      h = fmaf(aff[i][8], r2.x, h);  h = fmaf(aff[i][9], r2.y, h);
      h = fmaf(aff[i][10], r2.z, h); h = fmaf(aff[i][11], r2.w, h);
      h = fmaf(aff[i][12], r3.x, h); h = fmaf(aff[i][13], r3.y, h);
      h = fmaf(aff[i][14], r3.z, h); h = fmaf(aff[i][15], r3.w, h);
      h = fmaxf(h, 0.f);
      rc0[i] = fmaf(h, g.x, rc0[i]);
      rc1[i] = fmaf(h, g.y, rc1[i]);
      rc2[i] = fmaf(h, g.z, rc2[i]);
    }
  }

  // Errors + stores.
  float err[P];
#pragma unroll
  for (int i = 0; i < P; i++) {
    const float dx = px[i] - rc0[i], dy = py[i] - rc1[i], dz = pz[i] - rc2[i];
    err[i] = fmaf(dx, dx, fmaf(dy, dy, dz * dz));
    if (val[i]) {
      const int p = base + i * TPB + tid;
      float4* oa = (float4*)(out + O_AFF + (size_t)p * 16);
      oa[0] = make_float4(aff[i][0], aff[i][1], aff[i][2], aff[i][3]);
      oa[1] = make_float4(aff[i][4], aff[i][5], aff[i][6], aff[i][7]);
      oa[2] = make_float4(aff[i][8], aff[i][9], aff[i][10], aff[i][11]);
      oa[3] = make_float4(aff[i][12], aff[i][13], aff[i][14], aff[i][15]);
      float* orc = out + O_REC + (size_t)p * 3;
      orc[0] = rc0[i]; orc[1] = rc1[i]; orc[2] = rc2[i];
      out[O_SPA + p] = err[i];
    }
  }

  // --- segment reduction ---
  // Fast path: this thread's P points all valid & same seg, and seg is
  // wave-uniform (true for nearly all waves: segments average ~15.6k points).
  bool tok = true;
#pragma unroll
  for (int i = 0; i < P; i++) tok = tok && (seg[i] == seg[0]) && val[i];
  const int wseg = __shfl(seg[0], 0);
  const bool fast = __all(tok && (seg[0] == wseg));

  if (fast) {
    float v[18];
    v[0] = 0.f;
#pragma unroll
    for (int i = 0; i < P; i++) v[0] += err[i];
    v[1] = (float)P;
#pragma unroll
    for (int k = 0; k < AFFD; k++) {
      float s = 0.f;
#pragma unroll
      for (int i = 0; i < P; i++) s += aff[i][k];
      v[2 + k] = s;
    }
#pragma unroll
    for (int i = 0; i < 18; i++) {
      float x = v[i];
      x += __shfl_down(x, 32);
      x += __shfl_down(x, 16);
      x += __shfl_down(x, 8);
      x += __shfl_down(x, 4);
      x += __shfl_down(x, 2);
      x += __shfl_down(x, 1);
      v[i] = x;
    }
    if ((tid & 63) == 0) {
#pragma unroll
      for (int i = 0; i < 18; i++) atomicAdd(&ws[wseg * 18 + i], v[i]);
    }
  } else {
    // Slow path: handle each i-slice (64 consecutive points per wave).
#pragma unroll
    for (int i = 0; i < P; i++) {
      float v[18];
      v[0] = val[i] ? err[i] : 0.f;
      v[1] = val[i] ? 1.f : 0.f;
#pragma unroll
      for (int k = 0; k < AFFD; k++) v[2 + k] = val[i] ? aff[i][k] : 0.f;
      const int fi = __shfl(seg[i], 0);
      const bool uni = __all((seg[i] == fi) || !val[i]);
      if (uni) {
#pragma unroll
        for (int q = 0; q < 18; q++) {
          float x = v[q];
          x += __shfl_down(x, 32);
          x += __shfl_down(x, 16);
          x += __shfl_down(x, 8);
          x += __shfl_down(x, 4);
          x += __shfl_down(x, 2);
          x += __shfl_down(x, 1);
          v[q] = x;
        }
        if ((tid & 63) == 0) {
#pragma unroll
          for (int q = 0; q < 18; q++) atomicAdd(&ws[fi * 18 + q], v[q]);
        }
      } else if (val[i]) {
#pragma unroll
        for (int q = 0; q < 18; q++) atomicAdd(&ws[seg[i] * 18 + q], v[q]);
      }
    }
  }
}

// ---------------------------------------------------------------------------
// Kernel 2: one block per segment (64 blocks x 64 threads).
// ---------------------------------------------------------------------------
__global__ __launch_bounds__(64) void agent_kernel(
    const float* __restrict__ ws, const float* __restrict__ agent_h,
    const float* __restrict__ Wx, const float* __restrict__ Wh,
    const float* __restrict__ bx, const float* __restrict__ bh,
    const float* __restrict__ Wlat, const float* __restrict__ blat,
    const float* __restrict__ Wact, const float* __restrict__ bact,
    float* __restrict__ out) {
  const int b = blockIdx.x;   // segment
  const int t = threadIdx.x;  // 0..63
  __shared__ float sAff[AFFD];
  __shared__ float sHn[AH];
  __shared__ float sLat[AL];

  const float cnt = fmaxf(ws[b * 18 + 1], 1.f);
  if (t == 0) out[O_SIG + b] = ws[b * 18 + 0] / cnt;
  if (t < AFFD) sAff[t] = ws[b * 18 + 2 + t] / cnt;
  const float h_prev = agent_h[b * AH + t];
  __syncthreads();

  float pr  = bx[t] + bh[t];
  float pz  = bx[64 + t] + bh[64 + t];
  float pnx = bx[128 + t];
  float pnh = bh[128 + t];
#pragma unroll
  for (int k = 0; k < AFFD; k++) {
    const float a = sAff[k];
    pr  = fmaf(a, Wx[k * 192 + t], pr);
    pz  = fmaf(a, Wx[k * 192 + 64 + t], pz);
    pnx = fmaf(a, Wx[k * 192 + 128 + t], pnx);
  }
#pragma unroll
  for (int k = 0; k < AH; k++) {
    const float h = __shfl(h_prev, k);
    pr  = fmaf(h, Wh[k * 192 + t], pr);
    pz  = fmaf(h, Wh[k * 192 + 64 + t], pz);
    pnh = fmaf(h, Wh[k * 192 + 128 + t], pnh);
  }
  const float r = 1.f / (1.f + expf(-pr));
  const float z = 1.f / (1.f + expf(-pz));
  const float n = tanhf(pnx + r * pnh);
  const float hn = fmaf(1.f - z, n, z * h_prev);
  sHn[t] = hn;
  out[O_HN + b * AH + t] = hn;
  __syncthreads();

  if (t < AL) {
    float acc = blat[t];
#pragma unroll
    for (int k = 0; k < AH; k++) acc = fmaf(sHn[k], Wlat[k * AL + t], acc);
    sLat[t] = tanhf(acc);
  }
  __syncthreads();

  if (t < AA) {
    float acc = bact[t];
#pragma unroll
    for (int k = 0; k < AL; k++) acc = fmaf(sLat[k], Wact[k * AA + t], acc);
    out[O_ACT + b * AA + t] = acc;
  }
}

extern "C" void kernel_launch(void* const* d_in, const int* in_sizes, int n_in,
                              void* d_out, int out_size, void* d_ws, size_t ws_size,
                              hipStream_t stream) {
  const float* pos     = (const float*)d_in[0];
  const int*   batch   = (const int*)d_in[1];
  const float* agent_h = (const float*)d_in[2];
  // d_in[3], d_in[4]: coherence_*_prev — unused by the math.
  const float* Wf1  = (const float*)d_in[5];
  const float* bf1v = (const float*)d_in[6];
  const float* Wf2  = (const float*)d_in[7];
  const float* bf2v = (const float*)d_in[8];
  const float* Wg1  = (const float*)d_in[9];
  const float* bg1v = (const float*)d_in[10];
  const float* Wg2  = (const float*)d_in[11];
  const float* bg2v = (const float*)d_in[12];
  const float* Wx   = (const float*)d_in[13];
  const float* Wh   = (const float*)d_in[14];
  const float* bx   = (const float*)d_in[15];
  const float* bh   = (const float*)d_in[16];
  const float* Wlat = (const float*)d_in[17];
  const float* blat = (const float*)d_in[18];
  const float* Wact = (const float*)d_in[19];
  const float* bact = (const float*)d_in[20];
  float* out = (float*)d_out;
  float* ws = (float*)d_ws;

  // ws is re-poisoned 0xAA before every launch — zero the accumulators.
  hipMemsetAsync(ws, 0, B_SEG * 18 * sizeof(float), stream);

  const int nblk = (N_PTS + PTS_BLK - 1) / PTS_BLK;  // 1954
  point_kernel<<<nblk, TPB, 0, stream>>>(pos, batch, Wf1, bf1v, Wf2, bf2v,
                                         Wg1, bg1v, Wg2, bg2v, out, ws);
  agent_kernel<<<B_SEG, 64, 0, stream>>>(ws, agent_h, Wx, Wh, bx, bh,
                                         Wlat, blat, Wact, bact, out);
}

// Round 2
// 321.170 us; speedup vs baseline: 1.0336x; 1.0336x over previous
//
#include <hip/hip_runtime.h>
#include <stdint.h>

#define N_PTS 1000000
#define B_SEG 64
#define HID 128
#define AFFD 16
#define AH 64
#define AL 32
#define AA 8
#define TPB 128       // threads per block (2 waves)
#define P 4           // points per thread
#define PTS_BLK (TPB * P)  // 512

// Output flat offsets in FLOAT elements (return order: affordances, recon_pos,
// coh_signal, coh_spatial, agent_action, agent_h_next). Output dtype: float32.
#define O_AFF 0
#define O_REC (16 * N_PTS)
#define O_SIG (19 * N_PTS)
#define O_SPA (19 * N_PTS + B_SEG)
#define O_ACT (20 * N_PTS + B_SEG)
#define O_HN  (20 * N_PTS + B_SEG + B_SEG * AA)

// ---------------------------------------------------------------------------
// Kernel 1: per-point MLPs.
// R5 lesson: 256-thread blocks + launch_bounds(256,2) -> compiler squeezed to
//   128 VGPR and spilled the P=8 working set.
// R6 lesson: occupancy was the limiter (13.9%, grid-starved at 977 blocks).
// R7 lesson (this file's predecessor): launch_bounds(128,4) with 20.5 KiB LDS
//   is INFEASIBLE (LDS caps at 3.5 waves/EU); the allocator responded by
//   squeezing to 64 VGPR and spilling the ~110-reg P=4 working set
//   (VGPR_Count=64, +3MB scratch WRITE, 222 us > 204 us baseline).
// R8 (this round): make the 4-waves/EU request feasible and pin it.
//   (a) Phase-split LDS: stage F weights, compute F, re-stage same buffers
//       with G weights, compute G. LDS 20992 -> ~10304 B => 8 blocks/CU fits.
//   (b) amdgpu_waves_per_eu(4,4): budget exactly 128 VGPR, no 64-reg squeeze.
//   Occupancy ceiling: VGPR=>16 waves/CU, LDS=>30, grid supplies 15.3 (=48%).
// ws layout: [seg][18] = {err_sum, count, aff_sum[16]}   (fp32)
// ---------------------------------------------------------------------------
__global__ __launch_bounds__(TPB)
__attribute__((amdgpu_waves_per_eu(4, 4)))
void point_kernel(
    const float* __restrict__ pos, const int* __restrict__ batch,
    const float* __restrict__ Wf1, const float* __restrict__ bf1v,
    const float* __restrict__ Wf2, const float* __restrict__ bf2v,
    const float* __restrict__ Wg1, const float* __restrict__ bg1v,
    const float* __restrict__ Wg2, const float* __restrict__ bg2v,
    float* __restrict__ out, float* __restrict__ ws) {
  // Phase-shared buffers: F uses {sW=Wf2, sA=Wf1|bf1}; G re-stages
  // {sW=Wg1^T, sA=Wg2|bg1}.
  __shared__ float sW[HID * AFFD];  // 8 KiB
  __shared__ float sA[HID * 4];     // 2 KiB
  __shared__ float sBf2[AFFD];      // 64 B (persistent)

  const int tid = threadIdx.x;

  // ---- stage F weights ----
  {
    const float4* src = (const float4*)Wf2;  // contiguous [j][k]
    float4* dst = (float4*)sW;
#pragma unroll
    for (int i = tid; i < HID * AFFD / 4; i += TPB) dst[i] = src[i];
    for (int j = tid; j < HID; j += TPB) {
      sA[j * 4 + 0] = Wf1[0 * HID + j];
      sA[j * 4 + 1] = Wf1[1 * HID + j];
      sA[j * 4 + 2] = Wf1[2 * HID + j];
      sA[j * 4 + 3] = bf1v[j];
    }
    if (tid < AFFD) sBf2[tid] = bf2v[tid];
  }
  const float bg20 = bg2v[0], bg21 = bg2v[1], bg22 = bg2v[2];
  __syncthreads();

  const float4* sWv = (const float4*)sW;
  const float4* sAv = (const float4*)sA;

  const int base = blockIdx.x * PTS_BLK;

  float px[P], py[P], pz[P];
  int seg[P];
  bool val[P];
#pragma unroll
  for (int i = 0; i < P; i++) {
    int p = base + i * TPB + tid;
    val[i] = (p < N_PTS);
    if (!val[i]) p = N_PTS - 1;  // clamp: uniform control flow in hot loops
    px[i] = pos[p * 3 + 0];
    py[i] = pos[p * 3 + 1];
    pz[i] = pos[p * 3 + 2];
    seg[i] = batch[p];
  }

  float aff[P][AFFD];
#pragma unroll
  for (int i = 0; i < P; i++)
#pragma unroll
    for (int k = 0; k < AFFD; k++) aff[i][k] = sBf2[k];

  // F: 3 -> 128 (relu) -> 16.  5 broadcast LDS reads feed 80 FMAs.
#pragma unroll 2
  for (int j = 0; j < HID; j++) {
    const float4 w = sAv[j];
    const float4 r0 = sWv[j * 4 + 0];
    const float4 r1 = sWv[j * 4 + 1];
    const float4 r2 = sWv[j * 4 + 2];
    const float4 r3 = sWv[j * 4 + 3];
#pragma unroll
    for (int i = 0; i < P; i++) {
      float h = fmaf(px[i], w.x, fmaf(py[i], w.y, fmaf(pz[i], w.z, w.w)));
      h = fmaxf(h, 0.f);
      aff[i][0]  = fmaf(h, r0.x, aff[i][0]);  aff[i][1]  = fmaf(h, r0.y, aff[i][1]);
      aff[i][2]  = fmaf(h, r0.z, aff[i][2]);  aff[i][3]  = fmaf(h, r0.w, aff[i][3]);
      aff[i][4]  = fmaf(h, r1.x, aff[i][4]);  aff[i][5]  = fmaf(h, r1.y, aff[i][5]);
      aff[i][6]  = fmaf(h, r1.z, aff[i][6]);  aff[i][7]  = fmaf(h, r1.w, aff[i][7]);
      aff[i][8]  = fmaf(h, r2.x, aff[i][8]);  aff[i][9]  = fmaf(h, r2.y, aff[i][9]);
      aff[i][10] = fmaf(h, r2.z, aff[i][10]); aff[i][11] = fmaf(h, r2.w, aff[i][11]);
      aff[i][12] = fmaf(h, r3.x, aff[i][12]); aff[i][13] = fmaf(h, r3.y, aff[i][13]);
      aff[i][14] = fmaf(h, r3.z, aff[i][14]); aff[i][15] = fmaf(h, r3.w, aff[i][15]);
    }
  }

  // ---- re-stage with G weights (same buffers) ----
  __syncthreads();  // all reads of F weights done
  {
#pragma unroll
    for (int i = tid; i < HID * AFFD; i += TPB) {
      int j = i >> 4, k = i & 15;
      sW[i] = Wg1[k * HID + j];  // transposed: [j][k]
    }
    for (int j = tid; j < HID; j += TPB) {
      sA[j * 4 + 0] = Wg2[j * 3 + 0];
      sA[j * 4 + 1] = Wg2[j * 3 + 1];
      sA[j * 4 + 2] = Wg2[j * 3 + 2];
      sA[j * 4 + 3] = bg1v[j];
    }
  }
  __syncthreads();

  // G: 16 -> 128 (relu) -> 3.
  float rc0[P], rc1[P], rc2[P];
#pragma unroll
  for (int i = 0; i < P; i++) { rc0[i] = bg20; rc1[i] = bg21; rc2[i] = bg22; }
#pragma unroll 2
  for (int j = 0; j < HID; j++) {
    const float4 g = sAv[j];
    const float4 r0 = sWv[j * 4 + 0];
    const float4 r1 = sWv[j * 4 + 1];
    const float4 r2 = sWv[j * 4 + 2];
    const float4 r3 = sWv[j * 4 + 3];
#pragma unroll
    for (int i = 0; i < P; i++) {
      float h = g.w;
      h = fmaf(aff[i][0], r0.x, h);  h = fmaf(aff[i][1], r0.y, h);
      h = fmaf(aff[i][2], r0.z, h);  h = fmaf(aff[i][3], r0.w, h);
      h = fmaf(aff[i][4], r1.x, h);  h = fmaf(aff[i][5], r1.y, h);
      h = fmaf(aff[i][6], r1.z, h);  h = fmaf(aff[i][7], r1.w, h);
      h = fmaf(aff[i][8], r2.x, h);  h = fmaf(aff[i][9], r2.y, h);
      h = fmaf(aff[i][10], r2.z, h); h = fmaf(aff[i][11], r2.w, h);
      h = fmaf(aff[i][12], r3.x, h); h = fmaf(aff[i][13], r3.y, h);
      h = fmaf(aff[i][14], r3.z, h); h = fmaf(aff[i][15], r3.w, h);
      h = fmaxf(h, 0.f);
      rc0[i] = fmaf(h, g.x, rc0[i]);
      rc1[i] = fmaf(h, g.y, rc1[i]);
      rc2[i] = fmaf(h, g.z, rc2[i]);
    }
  }

  // Errors + stores.
  float err[P];
#pragma unroll
  for (int i = 0; i < P; i++) {
    const float dx = px[i] - rc0[i], dy = py[i] - rc1[i], dz = pz[i] - rc2[i];
    err[i] = fmaf(dx, dx, fmaf(dy, dy, dz * dz));
    if (val[i]) {
      const int p = base + i * TPB + tid;
      float4* oa = (float4*)(out + O_AFF + (size_t)p * 16);
      oa[0] = make_float4(aff[i][0], aff[i][1], aff[i][2], aff[i][3]);
      oa[1] = make_float4(aff[i][4], aff[i][5], aff[i][6], aff[i][7]);
      oa[2] = make_float4(aff[i][8], aff[i][9], aff[i][10], aff[i][11]);
      oa[3] = make_float4(aff[i][12], aff[i][13], aff[i][14], aff[i][15]);
      float* orc = out + O_REC + (size_t)p * 3;
      orc[0] = rc0[i]; orc[1] = rc1[i]; orc[2] = rc2[i];
      out[O_SPA + p] = err[i];
    }
  }

  // --- segment reduction ---
  // Fast path: this thread's P points all valid & same seg, and seg is
  // wave-uniform (true for nearly all waves: segments average ~15.6k points).
  bool tok = true;
#pragma unroll
  for (int i = 0; i < P; i++) tok = tok && (seg[i] == seg[0]) && val[i];
  const int wseg = __shfl(seg[0], 0);
  const bool fast = __all(tok && (seg[0] == wseg));

  if (fast) {
    float v[18];
    v[0] = 0.f;
#pragma unroll
    for (int i = 0; i < P; i++) v[0] += err[i];
    v[1] = (float)P;
#pragma unroll
    for (int k = 0; k < AFFD; k++) {
      float s = 0.f;
#pragma unroll
      for (int i = 0; i < P; i++) s += aff[i][k];
      v[2 + k] = s;
    }
#pragma unroll
    for (int i = 0; i < 18; i++) {
      float x = v[i];
      x += __shfl_down(x, 32);
      x += __shfl_down(x, 16);
      x += __shfl_down(x, 8);
      x += __shfl_down(x, 4);
      x += __shfl_down(x, 2);
      x += __shfl_down(x, 1);
      v[i] = x;
    }
    if ((tid & 63) == 0) {
#pragma unroll
      for (int i = 0; i < 18; i++) atomicAdd(&ws[wseg * 18 + i], v[i]);
    }
  } else {
    // Slow path: handle each i-slice (64 consecutive points per wave).
#pragma unroll
    for (int i = 0; i < P; i++) {
      float v[18];
      v[0] = val[i] ? err[i] : 0.f;
      v[1] = val[i] ? 1.f : 0.f;
#pragma unroll
      for (int k = 0; k < AFFD; k++) v[2 + k] = val[i] ? aff[i][k] : 0.f;
      const int fi = __shfl(seg[i], 0);
      const bool uni = __all((seg[i] == fi) || !val[i]);
      if (uni) {
#pragma unroll
        for (int q = 0; q < 18; q++) {
          float x = v[q];
          x += __shfl_down(x, 32);
          x += __shfl_down(x, 16);
          x += __shfl_down(x, 8);
          x += __shfl_down(x, 4);
          x += __shfl_down(x, 2);
          x += __shfl_down(x, 1);
          v[q] = x;
        }
        if ((tid & 63) == 0) {
#pragma unroll
          for (int q = 0; q < 18; q++) atomicAdd(&ws[fi * 18 + q], v[q]);
        }
      } else if (val[i]) {
#pragma unroll
        for (int q = 0; q < 18; q++) atomicAdd(&ws[seg[i] * 18 + q], v[q]);
      }
    }
  }
}

// ---------------------------------------------------------------------------
// Kernel 2: one block per segment (64 blocks x 64 threads).
// ---------------------------------------------------------------------------
__global__ __launch_bounds__(64) void agent_kernel(
    const float* __restrict__ ws, const float* __restrict__ agent_h,
    const float* __restrict__ Wx, const float* __restrict__ Wh,
    const float* __restrict__ bx, const float* __restrict__ bh,
    const float* __restrict__ Wlat, const float* __restrict__ blat,
    const float* __restrict__ Wact, const float* __restrict__ bact,
    float* __restrict__ out) {
  const int b = blockIdx.x;   // segment
  const int t = threadIdx.x;  // 0..63
  __shared__ float sAff[AFFD];
  __shared__ float sHn[AH];
  __shared__ float sLat[AL];

  const float cnt = fmaxf(ws[b * 18 + 1], 1.f);
  if (t == 0) out[O_SIG + b] = ws[b * 18 + 0] / cnt;
  if (t < AFFD) sAff[t] = ws[b * 18 + 2 + t] / cnt;
  const float h_prev = agent_h[b * AH + t];
  __syncthreads();

  float pr  = bx[t] + bh[t];
  float pz  = bx[64 + t] + bh[64 + t];
  float pnx = bx[128 + t];
  float pnh = bh[128 + t];
#pragma unroll
  for (int k = 0; k < AFFD; k++) {
    const float a = sAff[k];
    pr  = fmaf(a, Wx[k * 192 + t], pr);
    pz  = fmaf(a, Wx[k * 192 + 64 + t], pz);
    pnx = fmaf(a, Wx[k * 192 + 128 + t], pnx);
  }
#pragma unroll
  for (int k = 0; k < AH; k++) {
    const float h = __shfl(h_prev, k);
    pr  = fmaf(h, Wh[k * 192 + t], pr);
    pz  = fmaf(h, Wh[k * 192 + 64 + t], pz);
    pnh = fmaf(h, Wh[k * 192 + 128 + t], pnh);
  }
  const float r = 1.f / (1.f + expf(-pr));
  const float z = 1.f / (1.f + expf(-pz));
  const float n = tanhf(pnx + r * pnh);
  const float hn = fmaf(1.f - z, n, z * h_prev);
  sHn[t] = hn;
  out[O_HN + b * AH + t] = hn;
  __syncthreads();

  if (t < AL) {
    float acc = blat[t];
#pragma unroll
    for (int k = 0; k < AH; k++) acc = fmaf(sHn[k], Wlat[k * AL + t], acc);
    sLat[t] = tanhf(acc);
  }
  __syncthreads();

  if (t < AA) {
    float acc = bact[t];
#pragma unroll
    for (int k = 0; k < AL; k++) acc = fmaf(sLat[k], Wact[k * AA + t], acc);
    out[O_ACT + b * AA + t] = acc;
  }
}

extern "C" void kernel_launch(void* const* d_in, const int* in_sizes, int n_in,
                              void* d_out, int out_size, void* d_ws, size_t ws_size,
                              hipStream_t stream) {
  const float* pos     = (const float*)d_in[0];
  const int*   batch   = (const int*)d_in[1];
  const float* agent_h = (const float*)d_in[2];
  // d_in[3], d_in[4]: coherence_*_prev — unused by the math.
  const float* Wf1  = (const float*)d_in[5];
  const float* bf1v = (const float*)d_in[6];
  const float* Wf2  = (const float*)d_in[7];
  const float* bf2v = (const float*)d_in[8];
  const float* Wg1  = (const float*)d_in[9];
  const float* bg1v = (const float*)d_in[10];
  const float* Wg2  = (const float*)d_in[11];
  const float* bg2v = (const float*)d_in[12];
  const float* Wx   = (const float*)d_in[13];
  const float* Wh   = (const float*)d_in[14];
  const float* bx   = (const float*)d_in[15];
  const float* bh   = (const float*)d_in[16];
  const float* Wlat = (const float*)d_in[17];
  const float* blat = (const float*)d_in[18];
  const float* Wact = (const float*)d_in[19];
  const float* bact = (const float*)d_in[20];
  float* out = (float*)d_out;
  float* ws = (float*)d_ws;

  // ws is re-poisoned 0xAA before every launch — zero the accumulators.
  hipMemsetAsync(ws, 0, B_SEG * 18 * sizeof(float), stream);

  const int nblk = (N_PTS + PTS_BLK - 1) / PTS_BLK;  // 1954
  point_kernel<<<nblk, TPB, 0, stream>>>(pos, batch, Wf1, bf1v, Wf2, bf2v,
                                         Wg1, bg1v, Wg2, bg2v, out, ws);
  agent_kernel<<<B_SEG, 64, 0, stream>>>(ws, agent_h, Wx, Wh, bx, bh,
                                         Wlat, blat, Wact, bact, out);
}